// Round 1
// baseline (435.925 us; speedup 1.0000x reference)
//
#include <hip/hip_runtime.h>

// Problem constants (fixed by setup_inputs): b=16, h=w=128, c=64, heads=4
#define B_   16
#define C_   64
#define HH   128
#define WW   128
#define NN   (HH*WW)      // 16384
#define NH   4
#define HD   16
#define TILE 64
#define PAD  68           // LDS row pad: keeps 16B alignment, breaks bank-conflict strides

__device__ __forceinline__ float act_elu1(float v) {
    // elu(v)+1 : v>0 ? v+1 : exp(v)
    return v > 0.f ? v + 1.f : __expf(v);
}

// -log2(10000)/16
#define NEG_L2_10K_OVER16 (-0.8304820237218406f)

__global__ void zero_kernel(float* p, int n) {
    int i = blockIdx.x * 256 + threadIdx.x;
    if (i < n) p[i] = 0.f;
}

// Phase 1: k = elu(x@Wk^T+bk)+1 ; k_mean += k ; kv += k_rope^T v  (per head)
__global__ __launch_bounds__(256) void la_phase1(
    const float* __restrict__ x, const float* __restrict__ qk_w,
    const float* __restrict__ qk_b, float* __restrict__ g_kv,
    float* __restrict__ g_km)
{
    __shared__ float xs[TILE*PAD];
    __shared__ float wT[64*PAD];   // wT[c][j] = Wk[j][c]
    __shared__ float ks[TILE*PAD]; // roped k
    __shared__ float kmean[64];

    const int tid = threadIdx.x;
    const int b  = blockIdx.y;
    const int n0 = blockIdx.x * TILE;
    const int tx = tid & 15;
    const int ty = tid >> 4;

    if (tid < 64) kmean[tid] = 0.f;

    const float* xb = x + (size_t)b * (size_t)(NN * C_);

    // stage x tile + transposed Wk (rows 64..127 of qk_w)
    for (int idx = tid; idx < 1024; idx += 256) {
        const int flat = idx << 2;
        const int row = flat >> 6;
        const int col = flat & 63;
        const float4 xv = *(const float4*)(xb + (size_t)(n0 + row) * C_ + col);
        *(float4*)(xs + row*PAD + col) = xv;
        const float4 wv = *(const float4*)(qk_w + (64 + row)*64 + col);
        wT[(col+0)*PAD + row] = wv.x;
        wT[(col+1)*PAD + row] = wv.y;
        wT[(col+2)*PAD + row] = wv.z;
        wT[(col+3)*PAD + row] = wv.w;
    }
    __syncthreads();

    // 64x64 matmul, thread (ty,tx): positions ty+16m, channels 4tx..4tx+3
    float acc[4][4];
    #pragma unroll
    for (int m = 0; m < 4; ++m)
        #pragma unroll
        for (int j = 0; j < 4; ++j) acc[m][j] = 0.f;

    #pragma unroll 4
    for (int c = 0; c < 64; c += 4) {
        const float4 w0 = *(const float4*)(wT + (c+0)*PAD + 4*tx);
        const float4 w1 = *(const float4*)(wT + (c+1)*PAD + 4*tx);
        const float4 w2 = *(const float4*)(wT + (c+2)*PAD + 4*tx);
        const float4 w3 = *(const float4*)(wT + (c+3)*PAD + 4*tx);
        #pragma unroll
        for (int m = 0; m < 4; ++m) {
            const float4 xv = *(const float4*)(xs + (ty + 16*m)*PAD + c);
            acc[m][0] += xv.x*w0.x + xv.y*w1.x + xv.z*w2.x + xv.w*w3.x;
            acc[m][1] += xv.x*w0.y + xv.y*w1.y + xv.z*w2.y + xv.w*w3.y;
            acc[m][2] += xv.x*w0.z + xv.y*w1.z + xv.z*w2.z + xv.w*w3.z;
            acc[m][3] += xv.x*w0.w + xv.y*w1.w + xv.z*w2.w + xv.w*w3.w;
        }
    }

    const float4 bk = *(const float4*)(qk_b + 64 + 4*tx);
    // rope pairs owned by this thread: 2tx, 2tx+1
    const int pm0 = 2*tx, pm1 = 2*tx + 1;
    const float th0 = exp2f(NEG_L2_10K_OVER16 * (float)(pm0 < 16 ? pm0 : pm0 - 16));
    const float th1 = exp2f(NEG_L2_10K_OVER16 * (float)(pm1 < 16 ? pm1 : pm1 - 16));

    #pragma unroll
    for (int m = 0; m < 4; ++m) {
        const int p = ty + 16*m;
        const int n = n0 + p;
        const float yc = (float)(n >> 7);
        const float xc = (float)(n & 127);
        const float k0 = act_elu1(acc[m][0] + bk.x);
        const float k1 = act_elu1(acc[m][1] + bk.y);
        const float k2 = act_elu1(acc[m][2] + bk.z);
        const float k3 = act_elu1(acc[m][3] + bk.w);
        atomicAdd(&kmean[4*tx+0], k0);
        atomicAdd(&kmean[4*tx+1], k1);
        atomicAdd(&kmean[4*tx+2], k2);
        atomicAdd(&kmean[4*tx+3], k3);
        const float a0 = (pm0 < 16 ? yc : xc) * th0;
        const float a1 = (pm1 < 16 ? yc : xc) * th1;
        float s0, c0, s1, c1;
        __sincosf(a0, &s0, &c0);
        __sincosf(a1, &s1, &c1);
        float4 kr;
        kr.x = k0*c0 - k1*s0;
        kr.y = k0*s0 + k1*c0;
        kr.z = k2*c1 - k3*s1;
        kr.w = k2*s1 + k3*c1;
        *(float4*)(ks + p*PAD + 4*tx) = kr;
    }
    __syncthreads();

    // kv partial: thread -> (head, d, 4 e-values), reduce over 64 positions
    {
        const int h  = tid >> 6;
        const int d  = (tid >> 2) & 15;
        const int e4 = (tid & 3) << 2;
        float a0 = 0.f, a1 = 0.f, a2 = 0.f, a3 = 0.f;
        #pragma unroll 4
        for (int p = 0; p < TILE; ++p) {
            const float kr = ks[p*PAD + h*HD + d];
            const float4 xv = *(const float4*)(xs + p*PAD + h*HD + e4);
            a0 += kr*xv.x; a1 += kr*xv.y; a2 += kr*xv.z; a3 += kr*xv.w;
        }
        float* dst = g_kv + (((b*NH + h)*HD + d)*HD + e4);
        atomicAdd(dst+0, a0);
        atomicAdd(dst+1, a1);
        atomicAdd(dst+2, a2);
        atomicAdd(dst+3, a3);
    }

    if (tid < 64) atomicAdd(&g_km[b*64 + tid], kmean[tid]);
}

// Phase 2: q = elu(x@Wq^T+bq)+1 ; z = 1/(q.k_mean+eps) ; out = q_rope.kv*z + lepe
__global__ __launch_bounds__(256) void la_phase2(
    const float* __restrict__ x, const float* __restrict__ qk_w,
    const float* __restrict__ qk_b, const float* __restrict__ lepe_w,
    const float* __restrict__ lepe_b, const float* __restrict__ g_kv,
    const float* __restrict__ g_km, float* __restrict__ out)
{
    __shared__ float xs[TILE*PAD];
    __shared__ float wT[64*PAD];
    __shared__ float qs[TILE*PAD];      // roped q
    __shared__ float kvs[NH*HD*HD];     // kv * inv_n
    __shared__ float zs[TILE*NH];
    __shared__ float lws[9*64];         // lepe weights [tap][ch]

    const int tid = threadIdx.x;
    const int b  = blockIdx.y;
    const int n0 = blockIdx.x * TILE;
    const int tx = tid & 15;
    const int ty = tid >> 4;
    const float inv_n = 1.f / (float)NN;

    const float* xb = x + (size_t)b * (size_t)(NN * C_);

    for (int idx = tid; idx < 1024; idx += 256) {
        const int flat = idx << 2;
        const int row = flat >> 6;
        const int col = flat & 63;
        const float4 xv = *(const float4*)(xb + (size_t)(n0 + row) * C_ + col);
        *(float4*)(xs + row*PAD + col) = xv;
        const float4 wv = *(const float4*)(qk_w + row*64 + col);  // Wq rows 0..63
        wT[(col+0)*PAD + row] = wv.x;
        wT[(col+1)*PAD + row] = wv.y;
        wT[(col+2)*PAD + row] = wv.z;
        wT[(col+3)*PAD + row] = wv.w;
        kvs[idx] = g_kv[b*(NH*HD*HD) + idx] * inv_n;
    }
    for (int idx = tid; idx < 576; idx += 256) {
        lws[(idx % 9)*64 + (idx / 9)] = lepe_w[idx];
    }
    __syncthreads();

    float acc[4][4];
    #pragma unroll
    for (int m = 0; m < 4; ++m)
        #pragma unroll
        for (int j = 0; j < 4; ++j) acc[m][j] = 0.f;

    #pragma unroll 4
    for (int c = 0; c < 64; c += 4) {
        const float4 w0 = *(const float4*)(wT + (c+0)*PAD + 4*tx);
        const float4 w1 = *(const float4*)(wT + (c+1)*PAD + 4*tx);
        const float4 w2 = *(const float4*)(wT + (c+2)*PAD + 4*tx);
        const float4 w3 = *(const float4*)(wT + (c+3)*PAD + 4*tx);
        #pragma unroll
        for (int m = 0; m < 4; ++m) {
            const float4 xv = *(const float4*)(xs + (ty + 16*m)*PAD + c);
            acc[m][0] += xv.x*w0.x + xv.y*w1.x + xv.z*w2.x + xv.w*w3.x;
            acc[m][1] += xv.x*w0.y + xv.y*w1.y + xv.z*w2.y + xv.w*w3.y;
            acc[m][2] += xv.x*w0.z + xv.y*w1.z + xv.z*w2.z + xv.w*w3.z;
            acc[m][3] += xv.x*w0.w + xv.y*w1.w + xv.z*w2.w + xv.w*w3.w;
        }
    }

    const float4 bq = *(const float4*)(qk_b + 4*tx);
    const float4 km = *(const float4*)(g_km + b*64 + 4*tx);
    const int pm0 = 2*tx, pm1 = 2*tx + 1;
    const float th0 = exp2f(NEG_L2_10K_OVER16 * (float)(pm0 < 16 ? pm0 : pm0 - 16));
    const float th1 = exp2f(NEG_L2_10K_OVER16 * (float)(pm1 < 16 ? pm1 : pm1 - 16));

    #pragma unroll
    for (int m = 0; m < 4; ++m) {
        const int p = ty + 16*m;
        const int n = n0 + p;
        const float yc = (float)(n >> 7);
        const float xc = (float)(n & 127);
        const float q0 = act_elu1(acc[m][0] + bq.x);
        const float q1 = act_elu1(acc[m][1] + bq.y);
        const float q2 = act_elu1(acc[m][2] + bq.z);
        const float q3 = act_elu1(acc[m][3] + bq.w);
        // z denominator partial: q (pre-rope) . k_mean  (k_mean = g_km * inv_n)
        float dot = q0*km.x + q1*km.y + q2*km.z + q3*km.w;
        dot += __shfl_xor(dot, 1);
        dot += __shfl_xor(dot, 2);   // sum over the 4 lanes of this head's channel group
        if ((tx & 3) == 0) zs[p*NH + (tx >> 2)] = 1.f / (dot * inv_n + 1e-6f);
        const float a0 = (pm0 < 16 ? yc : xc) * th0;
        const float a1 = (pm1 < 16 ? yc : xc) * th1;
        float s0, c0, s1, c1;
        __sincosf(a0, &s0, &c0);
        __sincosf(a1, &s1, &c1);
        float4 qr;
        qr.x = q0*c0 - q1*s0;
        qr.y = q0*s0 + q1*c0;
        qr.z = q2*c1 - q3*s1;
        qr.w = q2*s1 + q3*c1;
        *(float4*)(qs + p*PAD + 4*tx) = qr;
    }
    __syncthreads();

    // out_attn: thread (ty,tx): positions ty+16m, out-channels 4tx..4tx+3 (head tx>>2)
    const int h  = tx >> 2;
    const int el = (tx & 3) << 2;   // e_local base within head
    float oa[4][4];
    #pragma unroll
    for (int m = 0; m < 4; ++m)
        #pragma unroll
        for (int j = 0; j < 4; ++j) oa[m][j] = 0.f;

    #pragma unroll 4
    for (int d = 0; d < HD; ++d) {
        const float4 kvv = *(const float4*)(kvs + (h*HD + d)*HD + el);
        #pragma unroll
        for (int m = 0; m < 4; ++m) {
            const float qv = qs[(ty + 16*m)*PAD + h*HD + d];
            oa[m][0] += qv*kvv.x;
            oa[m][1] += qv*kvv.y;
            oa[m][2] += qv*kvv.z;
            oa[m][3] += qv*kvv.w;
        }
    }

    const float4 lb = *(const float4*)(lepe_b + 4*tx);
    #pragma unroll
    for (int m = 0; m < 4; ++m) {
        const int p = ty + 16*m;
        const int n = n0 + p;
        const int yy = n >> 7;
        const int xc = n & 127;
        float l0 = lb.x, l1 = lb.y, l2 = lb.z, l3 = lb.w;
        #pragma unroll
        for (int dy = -1; dy <= 1; ++dy) {
            const int y2 = yy + dy;
            if ((unsigned)y2 >= HH) continue;
            #pragma unroll
            for (int dx = -1; dx <= 1; ++dx) {
                const int x2 = xc + dx;
                if ((unsigned)x2 >= WW) continue;
                const float4 xv = *(const float4*)(xb + (size_t)(y2*WW + x2)*C_ + 4*tx);
                const float4 wv = *(const float4*)(lws + ((dy+1)*3 + (dx+1))*64 + 4*tx);
                l0 += xv.x*wv.x; l1 += xv.y*wv.y; l2 += xv.z*wv.z; l3 += xv.w*wv.w;
            }
        }
        const float zv = zs[p*NH + h];
        float* op = out + (size_t)b*(size_t)(C_*NN) + n;
        op[(size_t)(4*tx+0)*NN] = oa[m][0]*zv + l0;
        op[(size_t)(4*tx+1)*NN] = oa[m][1]*zv + l1;
        op[(size_t)(4*tx+2)*NN] = oa[m][2]*zv + l2;
        op[(size_t)(4*tx+3)*NN] = oa[m][3]*zv + l3;
    }
}

extern "C" void kernel_launch(void* const* d_in, const int* in_sizes, int n_in,
                              void* d_out, int out_size, void* d_ws, size_t ws_size,
                              hipStream_t stream) {
    const float* x      = (const float*)d_in[0];
    // d_in[1], d_in[2] are h, w (fixed 128x128 — hardcoded)
    const float* qk_w   = (const float*)d_in[3];
    const float* qk_b   = (const float*)d_in[4];
    const float* lepe_w = (const float*)d_in[5];
    const float* lepe_b = (const float*)d_in[6];
    float* out = (float*)d_out;

    float* g_kv = (float*)d_ws;                 // B*NH*HD*HD = 16384 floats
    float* g_km = g_kv + B_*NH*HD*HD;           // B*64       = 1024 floats
    const int tot = B_*NH*HD*HD + B_*64;

    hipLaunchKernelGGL(zero_kernel, dim3((tot + 255)/256), dim3(256), 0, stream, g_kv, tot);
    hipLaunchKernelGGL(la_phase1, dim3(NN/TILE, B_), dim3(256), 0, stream,
                       x, qk_w, qk_b, g_kv, g_km);
    hipLaunchKernelGGL(la_phase2, dim3(NN/TILE, B_), dim3(256), 0, stream,
                       x, qk_w, qk_b, lepe_w, lepe_b, g_kv, g_km, out);
}

// Round 2
// 197.793 us; speedup vs baseline: 2.2039x; 2.2039x over previous
//
#include <hip/hip_runtime.h>

// Problem constants (fixed by setup_inputs): b=16, h=w=128, c=64, heads=4
#define B_   16
#define C_   64
#define HH   128
#define WW   128
#define NN   (HH*WW)      // 16384
#define NH   4
#define HD   16
#define PADB 72           // bf16 row pad: 144B rows -> 16B aligned, 2-way-max banks
#define PADO 66           // f32 out-staging pad

typedef short short8 __attribute__((ext_vector_type(8)));
typedef short short4v __attribute__((ext_vector_type(4)));
typedef float f32x4  __attribute__((ext_vector_type(4)));

__device__ __forceinline__ float act_elu1(float v) {
    return v > 0.f ? v + 1.f : __expf(v);   // elu(v)+1
}
__device__ __forceinline__ short f2bf(float f) {
    union { float f; unsigned u; } v; v.f = f;
    unsigned r = (v.u + 0x7FFFu + ((v.u >> 16) & 1u)) >> 16;  // RNE
    return (short)r;
}

// -log2(10000)/16
#define NEG_L2_10K_OVER16 (-0.8304820237218406f)

// ---------------------------------------------------------------------------
// Phase 1: k = elu(x@Wk^T+b)+1 ; per-block partials of kv = k_rope^T v and
// km = sum(k).  Each block: 256 positions (4 chunks of 64), MFMA everywhere.
// ---------------------------------------------------------------------------
__global__ __launch_bounds__(256) void la_phase1(
    const float* __restrict__ x, const float* __restrict__ qk_w,
    const float* __restrict__ qk_b, float* __restrict__ g_part)
{
    __shared__ __align__(16) char pool[4*64*PADB*2 + 256*4];
    short* sW  = (short*)pool;            // [64][72] Wk row-major (bf16)
    short* sX  = sW  + 64*PADB;           // [64][72] x tile row-major
    short* sXT = sX  + 64*PADB;           // [64][72] x tile transposed [ch][p]
    short* sKT = sXT + 64*PADB;           // [64][72] roped k transposed [ch][p]
    float* kmp = (float*)(sKT + 64*PADB); // [4][64]

    const int tid  = threadIdx.x;
    const int w    = tid >> 6;        // wave id = M-tile = head
    const int ln   = tid & 15;
    const int quad = (tid >> 4) & 3;
    const int b    = blockIdx.y;
    const int nblk = blockIdx.x;      // 0..63, 256 positions each
    const float* xb = x + (size_t)b * (size_t)(NN * C_);

    // stage Wk (rows 64..127 of qk_w), bf16
    #pragma unroll
    for (int it = 0; it < 4; ++it) {
        int idx = tid + 256*it;
        int row = idx & 63, k4 = (idx >> 6) << 2;
        float4 wv = *(const float4*)(qk_w + (64 + row)*64 + k4);
        short4v s4 = { f2bf(wv.x), f2bf(wv.y), f2bf(wv.z), f2bf(wv.w) };
        *(short4v*)(sW + row*PADB + k4) = s4;
    }

    float bias[4];
    #pragma unroll
    for (int nt = 0; nt < 4; ++nt) bias[nt] = qk_b[64 + 16*nt + ln];

    f32x4 acc2 = {0.f, 0.f, 0.f, 0.f};   // kv accumulator (head w), carried over chunks
    float kmacc[4] = {0.f, 0.f, 0.f, 0.f};

    for (int ck = 0; ck < 4; ++ck) {
        const int n0 = nblk*256 + ck*64;
        if (ck) __syncthreads();
        // stage x chunk: row-major + transposed
        #pragma unroll
        for (int it = 0; it < 4; ++it) {
            int idx = tid + 256*it;
            int row = idx & 63, k4 = (idx >> 6) << 2;
            float4 xv = *(const float4*)(xb + (size_t)(n0 + row)*C_ + k4);
            short4v s4 = { f2bf(xv.x), f2bf(xv.y), f2bf(xv.z), f2bf(xv.w) };
            *(short4v*)(sX + row*PADB + k4) = s4;
            sXT[(k4+0)*PADB + row] = s4.x;
            sXT[(k4+1)*PADB + row] = s4.y;
            sXT[(k4+2)*PADB + row] = s4.z;
            sXT[(k4+3)*PADB + row] = s4.w;
        }
        __syncthreads();

        // k-tile = X @ Wk^T via MFMA: M=64 pos, N=64 ch, K=64
        f32x4 acc[4];
        #pragma unroll
        for (int nt = 0; nt < 4; ++nt) acc[nt] = (f32x4){0.f,0.f,0.f,0.f};
        #pragma unroll
        for (int ks = 0; ks < 2; ++ks) {
            short8 a = *(const short8*)(sX + (16*w + ln)*PADB + 32*ks + 8*quad);
            #pragma unroll
            for (int nt = 0; nt < 4; ++nt) {
                short8 bf = *(const short8*)(sW + (16*nt + ln)*PADB + 32*ks + 8*quad);
                acc[nt] = __builtin_amdgcn_mfma_f32_16x16x32_bf16(a, bf, acc[nt], 0, 0, 0);
            }
        }

        // bias + elu + rope; write roped k transposed; accumulate km
        #pragma unroll
        for (int nt = 0; nt < 4; ++nt) {
            const int j = 16*nt + ln;          // global channel (C/D col)
            const int t = j >> 1;              // rope pair index
            const float theta = exp2f(NEG_L2_10K_OVER16 * (float)(t & 15));
            const bool isY = (t < 16);
            const float sgn = (j & 1) ? 1.f : -1.f;
            #pragma unroll
            for (int r = 0; r < 4; ++r) {
                float kval = act_elu1(acc[nt][r] + bias[nt]);
                kmacc[nt] += kval;
                float P = __shfl_xor(kval, 1);
                int p_loc = 16*w + 4*quad + r;
                int n = n0 + p_loc;
                float coord = isY ? (float)(n >> 7) : (float)(n & 127);
                float s, c;
                __sincosf(coord * theta, &s, &c);
                float kr = kval*c + sgn*P*s;   // even: v*c - P*s ; odd: P*s + v*c
                sKT[j*PADB + p_loc] = f2bf(kr);
            }
        }
        __syncthreads();

        // kv += k_rope^T v : per head (= wave w): D[d][e], K=64 positions
        #pragma unroll
        for (int ks = 0; ks < 2; ++ks) {
            short8 a  = *(const short8*)(sKT + (16*w + ln)*PADB + 32*ks + 8*quad);
            short8 bf = *(const short8*)(sXT + (16*w + ln)*PADB + 32*ks + 8*quad);
            acc2 = __builtin_amdgcn_mfma_f32_16x16x32_bf16(a, bf, acc2, 0, 0, 0);
        }
    }

    // store partials: [blk][1088] = 1024 kv + 64 km
    float* pb = g_part + (size_t)(b*64 + nblk) * 1088;
    #pragma unroll
    for (int r = 0; r < 4; ++r)
        pb[w*256 + (4*quad + r)*16 + ln] = acc2[r];

    #pragma unroll
    for (int nt = 0; nt < 4; ++nt) {
        float v = kmacc[nt];
        v += __shfl_xor(v, 16);
        v += __shfl_xor(v, 32);
        if ((tid & 63) < 16) kmp[w*64 + 16*nt + ln] = v;
    }
    __syncthreads();
    if (tid < 64)
        pb[1024 + tid] = kmp[tid] + kmp[64 + tid] + kmp[128 + tid] + kmp[192 + tid];
}

// ---------------------------------------------------------------------------
// Reduce: sum 64 per-block partials -> g_kv[b][1024], g_km[b][64]
// ---------------------------------------------------------------------------
__global__ __launch_bounds__(256) void la_reduce(
    const float* __restrict__ g_part, float* __restrict__ g_kv,
    float* __restrict__ g_km)
{
    int o = blockIdx.x * 256 + threadIdx.x;     // 0 .. 17407
    int b = o / 1088;
    int i = o - b * 1088;
    const float* p = g_part + (size_t)(b*64) * 1088 + i;
    float s = 0.f;
    #pragma unroll 8
    for (int nb = 0; nb < 64; ++nb) s += p[(size_t)nb * 1088];
    if (i < 1024) g_kv[b*1024 + i] = s;
    else          g_km[b*64 + (i - 1024)] = s;
}

// ---------------------------------------------------------------------------
// Phase 2: q = elu(x@Wq^T+b)+1 ; z ; out = q_rope@kv*z + lepe(3x3 dw conv)
// ---------------------------------------------------------------------------
__global__ __launch_bounds__(256) void la_phase2(
    const float* __restrict__ x, const float* __restrict__ qk_w,
    const float* __restrict__ qk_b, const float* __restrict__ lepe_w,
    const float* __restrict__ lepe_b, const float* __restrict__ g_kv,
    const float* __restrict__ g_km, float* __restrict__ out)
{
    __shared__ __align__(16) char pool[32768];
    short* sX   = (short*)pool;              // [64][72] (aliased by sOut later)
    short* sW   = sX + 64*PADB;              // [64][72]
    float* sOut = (float*)pool;              // [64][66] f32, aliases sX+sW
    short* sQ   = (short*)(pool + 18432);    // [64][72] roped q row-major [p][ch]
    short* sKVB = sQ + 64*PADB;              // [4*16][40] head-padded kv^T (bf16)

    const int tid  = threadIdx.x;
    const int w    = tid >> 6;
    const int ln   = tid & 15;
    const int quad = (tid >> 4) & 3;
    const int b    = blockIdx.y;
    const int n0   = blockIdx.x * 64;
    const float* xb = x + (size_t)b * (size_t)(NN * C_);
    const float inv_n = 1.f / (float)NN;

    #pragma unroll
    for (int it = 0; it < 4; ++it) {
        int idx = tid + 256*it;
        int row = idx & 63, k4 = (idx >> 6) << 2;
        float4 xv = *(const float4*)(xb + (size_t)(n0 + row)*C_ + k4);
        short4v s4 = { f2bf(xv.x), f2bf(xv.y), f2bf(xv.z), f2bf(xv.w) };
        *(short4v*)(sX + row*PADB + k4) = s4;
        float4 wv = *(const float4*)(qk_w + row*64 + k4);   // Wq rows 0..63
        short4v s5 = { f2bf(wv.x), f2bf(wv.y), f2bf(wv.z), f2bf(wv.w) };
        *(short4v*)(sW + row*PADB + k4) = s5;
    }
    // kv (normalized) into B-operand layout, zero-padded to K=32 per head pair
    for (int idx = tid; idx < 1024; idx += 256) {
        int h = idx >> 8, d = (idx >> 4) & 15, e = idx & 15;
        float v = g_kv[b*1024 + idx] * inv_n;
        int rowb = h*16 + e;
        int kpos  = (h & 1) ? 16 + d : d;
        int kzero = (h & 1) ? d : 16 + d;
        sKVB[rowb*40 + kpos]  = f2bf(v);
        sKVB[rowb*40 + kzero] = 0;
    }
    float biasq[4], kmv[4];
    #pragma unroll
    for (int nt = 0; nt < 4; ++nt) {
        biasq[nt] = qk_b[16*nt + ln];
        kmv[nt]   = g_km[b*64 + 16*nt + ln];
    }
    __syncthreads();

    // q-tile = X @ Wq^T via MFMA
    f32x4 acc[4];
    #pragma unroll
    for (int nt = 0; nt < 4; ++nt) acc[nt] = (f32x4){0.f,0.f,0.f,0.f};
    #pragma unroll
    for (int ks = 0; ks < 2; ++ks) {
        short8 a = *(const short8*)(sX + (16*w + ln)*PADB + 32*ks + 8*quad);
        #pragma unroll
        for (int nt = 0; nt < 4; ++nt) {
            short8 bf = *(const short8*)(sW + (16*nt + ln)*PADB + 32*ks + 8*quad);
            acc[nt] = __builtin_amdgcn_mfma_f32_16x16x32_bf16(a, bf, acc[nt], 0, 0, 0);
        }
    }

    // bias + elu + z + rope; write roped q row-major [p][ch]
    float z_all[4][4];
    #pragma unroll
    for (int nt = 0; nt < 4; ++nt) {
        const int j = 16*nt + ln;
        const int t = j >> 1;
        const float theta = exp2f(NEG_L2_10K_OVER16 * (float)(t & 15));
        const bool isY = (t < 16);
        const float sgn = (j & 1) ? 1.f : -1.f;
        #pragma unroll
        for (int r = 0; r < 4; ++r) {
            float qval = act_elu1(acc[nt][r] + biasq[nt]);
            float dotp = qval * kmv[nt];
            dotp += __shfl_xor(dotp, 1);
            dotp += __shfl_xor(dotp, 2);
            dotp += __shfl_xor(dotp, 4);
            dotp += __shfl_xor(dotp, 8);
            z_all[nt][r] = 1.f / (dotp * inv_n + 1e-6f);
            float P = __shfl_xor(qval, 1);
            int p_loc = 16*w + 4*quad + r;
            int n = n0 + p_loc;
            float coord = isY ? (float)(n >> 7) : (float)(n & 127);
            float s, c;
            __sincosf(coord * theta, &s, &c);
            float qr = qval*c + sgn*P*s;
            sQ[p_loc*PADB + j] = f2bf(qr);
        }
    }
    __syncthreads();   // sQ ready; also gates the sOut aliasing of sX/sW

    // out_attn = q_rope @ kv_n per head: M-tile w, all 4 heads (K=32, half-padded)
    f32x4 accq[4];
    #pragma unroll
    for (int h = 0; h < 4; ++h) accq[h] = (f32x4){0.f,0.f,0.f,0.f};
    #pragma unroll
    for (int P2 = 0; P2 < 2; ++P2) {
        short8 a = *(const short8*)(sQ + (16*w + ln)*PADB + 32*P2 + 8*quad);
        #pragma unroll
        for (int hh = 0; hh < 2; ++hh) {
            int h = 2*P2 + hh;
            short8 bf = *(const short8*)(sKVB + (h*16 + ln)*40 + 8*quad);
            accq[h] = __builtin_amdgcn_mfma_f32_16x16x32_bf16(a, bf, accq[h], 0, 0, 0);
        }
    }
    // scale by z, stage transposed for coalesced store
    #pragma unroll
    for (int h = 0; h < 4; ++h)
        #pragma unroll
        for (int r = 0; r < 4; ++r)
            sOut[(16*h + ln)*PADO + 16*w + 4*quad + r] = accq[h][r] * z_all[h][r];
    __syncthreads();

    // lepe conv (register sliding window) + combine + coalesced store
    const int ch = tid >> 2, sub = tid & 3, p0 = 16*sub;
    const int yy = n0 >> 7, xbase = n0 & 127, gx0 = xbase + p0;
    float wv9[9];
    #pragma unroll
    for (int tap = 0; tap < 9; ++tap) wv9[tap] = lepe_w[ch*9 + tap];
    const float lb = lepe_b[ch];
    float accl[16];
    #pragma unroll
    for (int j = 0; j < 16; ++j) accl[j] = 0.f;
    #pragma unroll
    for (int dy = -1; dy <= 1; ++dy) {
        int y2 = yy + dy;
        if ((unsigned)y2 >= HH) continue;
        const float* rp = xb + (size_t)(y2*WW)*C_ + ch;
        float cb[18];
        #pragma unroll
        for (int jj = 0; jj < 18; ++jj) {
            int col = gx0 - 1 + jj;
            cb[jj] = ((unsigned)col < WW) ? rp[(size_t)col*C_] : 0.f;
        }
        float w0 = wv9[(dy+1)*3 + 0], w1 = wv9[(dy+1)*3 + 1], w2 = wv9[(dy+1)*3 + 2];
        #pragma unroll
        for (int j = 0; j < 16; ++j)
            accl[j] += cb[j]*w0 + cb[j+1]*w1 + cb[j+2]*w2;
    }
    float* outp = out + (size_t)b*(size_t)(C_*NN) + (size_t)ch*NN + n0 + p0;
    #pragma unroll
    for (int g = 0; g < 4; ++g) {
        float2 a0 = *(const float2*)(sOut + ch*PADO + p0 + 4*g);
        float2 a1 = *(const float2*)(sOut + ch*PADO + p0 + 4*g + 2);
        float4 o4 = { a0.x + accl[4*g+0] + lb, a0.y + accl[4*g+1] + lb,
                      a1.x + accl[4*g+2] + lb, a1.y + accl[4*g+3] + lb };
        *(float4*)(outp + 4*g) = o4;
    }
}

extern "C" void kernel_launch(void* const* d_in, const int* in_sizes, int n_in,
                              void* d_out, int out_size, void* d_ws, size_t ws_size,
                              hipStream_t stream) {
    const float* x      = (const float*)d_in[0];
    // d_in[1], d_in[2] are h, w (fixed 128x128 — hardcoded)
    const float* qk_w   = (const float*)d_in[3];
    const float* qk_b   = (const float*)d_in[4];
    const float* lepe_w = (const float*)d_in[5];
    const float* lepe_b = (const float*)d_in[6];
    float* out = (float*)d_out;

    float* g_part = (float*)d_ws;                    // 1024 * 1088 floats
    float* g_kv   = g_part + 1024*1088;              // 16 * 1024
    float* g_km   = g_kv + 16*1024;                  // 16 * 64

    hipLaunchKernelGGL(la_phase1, dim3(64, B_), dim3(256), 0, stream,
                       x, qk_w, qk_b, g_part);
    hipLaunchKernelGGL(la_reduce, dim3(68), dim3(256), 0, stream,
                       g_part, g_kv, g_km);
    hipLaunchKernelGGL(la_phase2, dim3(256, B_), dim3(256), 0, stream,
                       x, qk_w, qk_b, lepe_w, lepe_b, g_kv, g_km, out);
}